// Round 7
// baseline (48967.795 us; speedup 1.0000x reference)
//
#include <hip/hip_runtime.h>
#include <hip/hip_bf16.h>

typedef __bf16 bf16;
typedef __bf16 bf16x8 __attribute__((ext_vector_type(8)));
typedef float f32x4 __attribute__((ext_vector_type(4)));
typedef float f32x16 __attribute__((ext_vector_type(16)));
typedef unsigned u32x2 __attribute__((ext_vector_type(2)));

#define S_ 512
#define N_ 64
#define C_ 512
#define V_ 10
#define Q_ 256

// ======== main-path workspace layout (bytes) ========
#define OFF_A0   ((size_t)0)
#define OFF_A1   (OFF_A0 + (size_t)S_ * N_ * 4)
#define OFF_QU   (OFF_A1 + (size_t)S_ * N_ * 4)            // bf16 [Q][N][C]
#define OFF_HGU  (OFF_QU + (size_t)Q_ * N_ * C_ * 2)       // u32 [8][2][16][C] tagged h
#define OFF_HFB  (OFF_HGU + (size_t)8 * 2 * 16 * C_ * 4)   // bf16 [2][N][C] (fallback H)
#define OFF_CTRL (OFF_HFB + (size_t)2 * N_ * C_ * 2)       // 4KB: [0]=fail, +64 fb flags, +256 rec flags
#define OFF_HS   (OFF_CTRL + 4096)                         // bf16 [Q][N][C]
#define OFF_WB   (OFF_HS + (size_t)Q_ * N_ * C_ * 2)       // bf16 [2][4C][C]
#define OFF_PW   (OFF_WB + (size_t)2 * 4 * C_ * C_ * 2)    // bf16 [N][Q][S] (dead after k_queue)
#define OFF_GX   (OFF_PW)                                  // bf16 [Q*N][4C] overlays PW
#define OFF_END  (OFF_GX + (size_t)Q_ * N_ * 4 * C_ * 2)

// ======== fallback (small-ws) layout ========
#define FB_A0   ((size_t)0)
#define FB_A1   (FB_A0 + (size_t)S_ * N_ * 4)
#define FB_PW   (FB_A1 + (size_t)S_ * N_ * 4)
#define FB_QU   (FB_PW + (size_t)N_ * Q_ * S_ * 2)
#define FB_H    (FB_QU + (size_t)Q_ * N_ * C_ * 2)
#define FB_HS   (FB_H + (size_t)2 * N_ * C_ * 2)
#define FB_BAR  (FB_HS + (size_t)Q_ * N_ * C_ * 2)

__device__ __forceinline__ float sigf(float x) { return 1.f / (1.f + __expf(-x)); }
__device__ __forceinline__ float tanhf_(float x) { return 1.f - 2.f / (__expf(2.f * x) + 1.f); }
__device__ __forceinline__ float bu2f(unsigned u) { return __uint_as_float(u << 16); }

// ---------------- stage 1: action softmax ----------------
__global__ __launch_bounds__(256) void k_actions(const float* __restrict__ mem,
    const float* __restrict__ Wact, const float* __restrict__ bact,
    float* __restrict__ A0, float* __restrict__ A1) {
  const int wid = threadIdx.x >> 6, lane = threadIdx.x & 63;
  const int row = blockIdx.x * 4 + wid;          // row = s*64 + n
  const int s = row >> 6, n = row & 63;
  const float* mrow = mem + (size_t)row * C_ + lane * 8;
  const float* wrow = Wact + (size_t)lane * 16;
  float4 m0 = *(const float4*)(mrow);
  float4 m1 = *(const float4*)(mrow + 4);
  float d0 = 0.f, d1 = 0.f;
  float mv[8] = {m0.x, m0.y, m0.z, m0.w, m1.x, m1.y, m1.z, m1.w};
#pragma unroll
  for (int j = 0; j < 8; ++j) {
    d0 += mv[j] * wrow[j * 2 + 0];
    d1 += mv[j] * wrow[j * 2 + 1];
  }
#pragma unroll
  for (int m = 32; m >= 1; m >>= 1) {
    d0 += __shfl_xor(d0, m);
    d1 += __shfl_xor(d1, m);
  }
  if (lane == 0) {
    float l0 = d0 + bact[0], l1 = d1 + bact[1];
    float mx = fmaxf(l0, l1);
    float e0 = __expf(l0 - mx), e1 = __expf(l1 - mx);
    float inv = 1.f / (e0 + e1);
    A0[(size_t)n * S_ + s] = e0 * inv;
    A1[(size_t)n * S_ + s] = e1 * inv;
  }
}

// ---------------- stage 2: posvec scan ----------------
__global__ __launch_bounds__(256) void k_posvec(const float* __restrict__ A0,
    const float* __restrict__ A1, bf16* __restrict__ Pw) {
  __shared__ float a0s[S_], a1s[S_];
  __shared__ float pbuf[2][Q_];
  const int n = blockIdx.x, t = threadIdx.x;
  a0s[t] = A0[(size_t)n * S_ + t];
  a0s[t + 256] = A0[(size_t)n * S_ + t + 256];
  a1s[t] = A1[(size_t)n * S_ + t];
  a1s[t + 256] = A1[(size_t)n * S_ + t + 256];
  float p = (t == 0) ? 1.f : 0.f;
  __syncthreads();
  for (int s8 = 0; s8 < S_; s8 += 8) {
    float emit[8];
#pragma unroll
    for (int jj = 0; jj < 8; ++jj) {
      const int s = s8 + jj;
      pbuf[jj & 1][t] = p;
      __syncthreads();
      float pm1 = pbuf[jj & 1][(t + Q_ - 1) & (Q_ - 1)];
      float a0 = a0s[s], a1 = a1s[s];
      emit[jj] = p * a1;
      p = fmaf(pm1, a1, p * a0);
    }
    bf16x8 v;
#pragma unroll
    for (int jj = 0; jj < 8; ++jj) v[jj] = (bf16)emit[jj];
    *(bf16x8*)(Pw + ((size_t)n * Q_ + t) * S_ + s8) = v;
  }
}

// ---------------- stage 3: queue einsum ----------------
__global__ __launch_bounds__(256) void k_queue(const bf16* __restrict__ Pw,
    const float* __restrict__ mem, bf16* __restrict__ qout) {
  __shared__ bf16 bt[64 * 32];
  const int bid = blockIdx.x;
  const int n = bid >> 5, qt = (bid >> 3) & 3, ct = bid & 7;
  const int q0 = qt * 64, c0 = ct * 64;
  const int t = threadIdx.x, wid = t >> 6, lane = t & 63;
  const int lrow = lane & 15, lkb = lane >> 4;
  f32x4 acc[4] = {};
  const bf16* arow = Pw + ((size_t)n * Q_ + q0 + wid * 16 + lrow) * S_ + lkb * 8;
  const int sl = t >> 3, cb = (t & 7) * 8;
  const float* msrc = mem + ((size_t)sl * N_ + n) * C_ + c0 + cb;
  for (int kb = 0; kb < 16; ++kb) {
    float4 f0 = *(const float4*)(msrc + (size_t)kb * 32 * N_ * C_);
    float4 f1 = *(const float4*)(msrc + (size_t)kb * 32 * N_ * C_ + 4);
    __syncthreads();
    float fv[8] = {f0.x, f0.y, f0.z, f0.w, f1.x, f1.y, f1.z, f1.w};
#pragma unroll
    for (int jw = 0; jw < 8; ++jw) {
      const int row = cb + jw;
      bt[row * 32 + ((((sl >> 3) ^ (row & 3)) << 3) | (sl & 7))] = (bf16)fv[jw];
    }
    __syncthreads();
    bf16x8 a = *(const bf16x8*)(arow + kb * 32);
#pragma unroll
    for (int cs = 0; cs < 4; ++cs) {
      const int row = cs * 16 + lrow;
      bf16x8 b = *(const bf16x8*)(&bt[row * 32 + ((lkb ^ (row & 3)) << 3)]);
      acc[cs] = __builtin_amdgcn_mfma_f32_16x16x32_bf16(a, b, acc[cs], 0, 0, 0);
    }
  }
#pragma unroll
  for (int cs = 0; cs < 4; ++cs) {
#pragma unroll
    for (int r = 0; r < 4; ++r) {
      const int q = q0 + wid * 16 + (lane >> 4) * 4 + r;
      const int c = c0 + cs * 16 + lrow;
      qout[((size_t)q * N_ + n) * C_ + c] = (bf16)acc[cs][r];
    }
  }
}

// ---------------- stage 3.5: weight convert fp32 -> bf16 ----------------
__global__ __launch_bounds__(256) void k_cvtw(const float* __restrict__ Wih,
    const float* __restrict__ Whh, bf16* __restrict__ Wb) {
  const int bid = blockIdx.x;
  const int p = bid >> 9, rem = bid & 511;
  const size_t off = (size_t)rem * 2048 + (size_t)threadIdx.x * 8;
  const float* src = (p ? Whh : Wih) + off;
  float4 a = *(const float4*)src;
  float4 b = *(const float4*)(src + 4);
  bf16x8 v;
  v[0] = (bf16)a.x; v[1] = (bf16)a.y; v[2] = (bf16)a.z; v[3] = (bf16)a.w;
  v[4] = (bf16)b.x; v[5] = (bf16)b.y; v[6] = (bf16)b.z; v[7] = (bf16)b.w;
  *(bf16x8*)(Wb + (size_t)p * (4 * C_ * C_) + off) = v;
}

// ---------------- stage 3.6: GX = queue @ W_ih^T + (bih+bhh) ----------------
// GX[q*64+n][col'] with col' = ch*4 + gate (gate 0=i,1=f,2=g,3=o).
__global__ __launch_bounds__(256) void k_gx(const bf16* __restrict__ qu,
    const bf16* __restrict__ Wb, const float* __restrict__ bih,
    const float* __restrict__ bhh, bf16* __restrict__ GX) {
  const int bid = blockIdx.x;
  const int mt = bid >> 5, ct = bid & 31;
  const int t = threadIdx.x, wid = t >> 6, lane = t & 63;
  const int r0 = mt * 64 + wid * 16;
  const int lrow = lane & 15, lk = (lane >> 4) * 8;
  const bf16* arow = qu + (size_t)(r0 + lrow) * C_ + lk;
  int wrows[4]; float biasv[4];
#pragma unroll
  for (int cs = 0; cs < 4; ++cs) {
    const int jp = ct * 64 + cs * 16 + lrow;
    const int wr = (jp & 3) * 512 + (jp >> 2);
    wrows[cs] = wr;
    biasv[cs] = bih[wr] + bhh[wr];
  }
  f32x4 acc[4] = {};
  for (int kb = 0; kb < 16; ++kb) {
    bf16x8 a = *(const bf16x8*)(arow + kb * 32);
#pragma unroll
    for (int cs = 0; cs < 4; ++cs) {
      bf16x8 b = *(const bf16x8*)(Wb + (size_t)wrows[cs] * C_ + kb * 32 + lk);
      acc[cs] = __builtin_amdgcn_mfma_f32_16x16x32_bf16(a, b, acc[cs], 0, 0, 0);
    }
  }
#pragma unroll
  for (int cs = 0; cs < 4; ++cs)
#pragma unroll
    for (int r = 0; r < 4; ++r) {
      const int row = r0 + (lane >> 4) * 4 + r;
      const int col = ct * 64 + cs * 16 + lrow;
      GX[(size_t)row * 2048 + col] = (bf16)(acc[cs][r] + biasv[cs]);
    }
}

// ---------------- stage 4: per-XCD recurrence (group = bid%8) ----------------
// 8 groups x 16 WGs; group g owns n in [8g,8g+8); WG slot ws owns h-ch [ws*32,ws*32+32).
// h exchanged as u32 (tag<<16)|bf16 through the (presumed) XCD-local L2 via sc0.
// Flags advisory (capped); tags self-verify; any expiry -> failFlag -> gated fallback.
#define RLOAD_H                                                                \
  {                                                                            \
    _Pragma("unroll") for (int ks_ = 0; ks_ < 16; ++ks_) {                     \
      asm volatile("global_load_dwordx4 %0, %1, off offset:%2 sc0"             \
                   : "=v"(hw[ks_ * 2]) : "v"(hbase), "i"(ks_ * 128));          \
      asm volatile("global_load_dwordx4 %0, %1, off offset:%2 sc0"             \
                   : "=v"(hw[ks_ * 2 + 1]) : "v"(hbase), "i"(ks_ * 128 + 16)); \
    }                                                                          \
    asm volatile("s_waitcnt vmcnt(0)" ::: "memory");                           \
    __builtin_amdgcn_sched_barrier(0);                                         \
  }

__global__ __launch_bounds__(256, 1) void k_rec(const bf16* __restrict__ Wb,
    const bf16* __restrict__ GX, unsigned* __restrict__ Hg,
    bf16* __restrict__ hs, int* __restrict__ ctrl) {
  __shared__ float gbuf[8][132];
  __shared__ int ldsCnt[Q_];
  const int bid = blockIdx.x, t = threadIdx.x;
  const int wid = t >> 6, lane = t & 63;
  const int g = bid & 7, ws = bid >> 3;       // group (XCD), slot 0..15
  int* flg = ctrl + 256 + g * 16;
  unsigned* hg = Hg + (size_t)g * 2 * 16 * C_;
  const bf16* Whhb = Wb + (size_t)4 * C_ * C_;

  // W_hh B-fragments -> registers (128 VGPR)
  bf16x8 bw[2][16];
#pragma unroll
  for (int ct = 0; ct < 2; ++ct) {
    const int col = ws * 128 + wid * 32 + ct * 16 + (lane & 15);
    const int wr = (col & 3) * 512 + (col >> 2);
    const bf16* src = Whhb + (size_t)wr * C_ + (lane >> 4) * 8;
#pragma unroll
    for (int ks = 0; ks < 16; ++ks) bw[ct][ks] = *(const bf16x8*)(src + ks * 32);
  }
  ldsCnt[t] = 0;
  const int n_e = t >> 5, ch_l = t & 31, c0 = ws * 32;
  {  // init own slice: parity0 rows0-7 = h0 (tag0); rows 8-15 both parities = tag0/zero
    unsigned z = 0;
    unsigned* p0 = hg + (size_t)(0 * 16 + n_e) * C_ + c0 + ch_l;
    unsigned* pa = hg + (size_t)(0 * 16 + 8 + n_e) * C_ + c0 + ch_l;
    unsigned* pb = hg + (size_t)(1 * 16 + 8 + n_e) * C_ + c0 + ch_l;
    asm volatile("global_store_dword %0, %1, off sc0" :: "v"(p0), "v"(z) : "memory");
    asm volatile("global_store_dword %0, %1, off sc0" :: "v"(pa), "v"(z) : "memory");
    asm volatile("global_store_dword %0, %1, off sc0" :: "v"(pb), "v"(z) : "memory");
    asm volatile("s_waitcnt vmcnt(0)" ::: "memory");
  }
  __syncthreads();
  if (t == 0) {
    int one = 1; int* fp = flg + ws;
    asm volatile("global_store_dword %0, %1, off sc0" :: "v"(fp), "v"(one) : "memory");
  }

  float cst = 0.f;
  unsigned badf = 0;
  u32x2 gxr;
  {  // GX for step 0
    const bf16* gp = GX + (size_t)(g * 8 + n_e) * 2048 + (c0 + ch_l) * 4;
    gxr = *(const u32x2*)gp;
  }
  const int arow = lane & 15;

  for (int step = 0; step < Q_; ++step) {
    const int cur = step & 1, nxt = cur ^ 1;
    if (wid == 0) {  // advisory capped poll
      int v, it = 0;
      int* fa = flg + (lane & 15);
      do {
        asm volatile("global_load_dword %0, %1, off sc0" : "=v"(v) : "v"(fa));
        asm volatile("s_waitcnt vmcnt(0)" ::: "memory");
      } while (__any(v < step + 1) && ++it < 512);
      if (__any(v < step + 1)) badf = 1;
    }
    __syncthreads();  // B1

    // tagged h load + verify (retry capped) + pack + MFMA
    unsigned* hbase = hg + (size_t)(cur * 16 + arow) * C_ + (lane >> 4) * 8;
    uint4 hw[32];
    RLOAD_H;
    {
      int tries = 0;
      const unsigned want = (unsigned)step << 16;
      while (true) {
        unsigned a_ = 0;
#pragma unroll
        for (int i_ = 0; i_ < 32; ++i_) {
          a_ |= (hw[i_].x ^ want); a_ |= (hw[i_].y ^ want);
          a_ |= (hw[i_].z ^ want); a_ |= (hw[i_].w ^ want);
        }
        const int ok = (arow >= 8) || (a_ < 0x10000u);
        if (__all(ok)) break;
        if (++tries >= 64) { badf = 1; break; }
        RLOAD_H;
      }
    }
    f32x4 acc0 = {0.f, 0.f, 0.f, 0.f}, acc1 = {0.f, 0.f, 0.f, 0.f};
#pragma unroll
    for (int ks = 0; ks < 16; ++ks) {
      union { unsigned u[4]; bf16x8 v; } pk;
      const uint4 w0 = hw[ks * 2], w1 = hw[ks * 2 + 1];
      pk.u[0] = (w0.y << 16) | (w0.x & 0xffffu);
      pk.u[1] = (w0.w << 16) | (w0.z & 0xffffu);
      pk.u[2] = (w1.y << 16) | (w1.x & 0xffffu);
      pk.u[3] = (w1.w << 16) | (w1.z & 0xffffu);
      acc0 = __builtin_amdgcn_mfma_f32_16x16x32_bf16(pk.v, bw[0][ks], acc0, 0, 0, 0);
      acc1 = __builtin_amdgcn_mfma_f32_16x16x32_bf16(pk.v, bw[1][ks], acc1, 0, 0, 0);
    }
#pragma unroll
    for (int r = 0; r < 4; ++r) {
      const int row = (lane >> 4) * 4 + r;
      if (row < 8) {
        gbuf[row][wid * 32 + (lane & 15)] = acc0[r];
        gbuf[row][wid * 32 + 16 + (lane & 15)] = acc1[r];
      }
    }
    __syncthreads();  // S1

    {  // elementwise + stores + GX prefetch
      const float gi = gbuf[n_e][ch_l * 4 + 0] + bu2f(gxr.x & 0xffffu);
      const float gf = gbuf[n_e][ch_l * 4 + 1] + bu2f(gxr.x >> 16);
      const float gg = gbuf[n_e][ch_l * 4 + 2] + bu2f(gxr.y & 0xffffu);
      const float go = gbuf[n_e][ch_l * 4 + 3] + bu2f(gxr.y >> 16);
      u32x2 gx2 = gxr;
      if (step + 1 < Q_) {
        const bf16* gp = GX + ((size_t)(step + 1) * N_ + g * 8 + n_e) * 2048 + (c0 + ch_l) * 4;
        asm volatile("global_load_dwordx2 %0, %1, off" : "=v"(gx2) : "v"(gp));
      }
      cst = sigf(gf) * cst + sigf(gi) * tanhf_(gg);
      const float hv = sigf(go) * tanhf_(cst);
      const bf16 hb16 = (bf16)hv;
      const unsigned hu = ((unsigned)(step + 1) << 16) |
                          (unsigned)__builtin_bit_cast(unsigned short, hb16);
      unsigned* hp = hg + (size_t)(nxt * 16 + n_e) * C_ + c0 + ch_l;
      asm volatile("global_store_dword %0, %1, off sc0" :: "v"(hp), "v"(hu) : "memory");
      unsigned short hss = __builtin_bit_cast(unsigned short, hb16);
      bf16* hq = hs + ((size_t)step * N_ + g * 8 + n_e) * C_ + c0 + ch_l;
      asm volatile("global_store_short %0, %1, off" :: "v"(hq), "v"(hss) : "memory");
      asm volatile("s_waitcnt vmcnt(1)" ::: "memory");  // gx2 + h-store acked; hs may linger
      gxr = gx2;
    }
    if (lane == 0) {  // per-WG fan-in -> flag
      if (atomicAdd(&ldsCnt[step], 1) == 3 && step + 1 < Q_) {
        int fv = step + 2; int* fp = flg + ws;
        asm volatile("global_store_dword %0, %1, off sc0" :: "v"(fp), "v"(fv) : "memory");
      }
    }
  }
  if (t == 0 && badf) atomicOr(ctrl, 1);
}

// ---------------- stage 4 fallback: R4 LSTM (gated by failFlag unless forced) ----------------
__global__ __launch_bounds__(256, 1) void k_lstm_fb(
    const bf16* __restrict__ queue, const float* __restrict__ Wih,
    const float* __restrict__ Whh, const float* __restrict__ bih,
    const float* __restrict__ bhh, bf16* __restrict__ H,
    bf16* __restrict__ hs, int* __restrict__ ctrl, int force) {
  if (!force &&
      __hip_atomic_load(ctrl, __ATOMIC_RELAXED, __HIP_MEMORY_SCOPE_AGENT) == 0)
    return;
  const int bid = blockIdx.x, t = threadIdx.x;
  __shared__ float gx[2][2][32][33];
  __shared__ float gh[2][32][33];
  __shared__ float bias[32];
  __shared__ int ldsCnt[Q_];
  __shared__ int ldsCnt0;
  int* flags = ctrl + 64;
  const int w = bid;
  const int wid = t >> 6, lane = t & 63;
  const int mat = wid >> 1;
  const int blk = wid & 1;

  const int col = lane & 31;
  const int kg = (lane >> 5) * 8;
  const int wr = (col & 3) * 512 + w * 8 + (col >> 2);
  const float* Wsrc = (mat ? Whh : Wih) + (size_t)wr * C_ + kg;
  bf16x8 bw[32];
#pragma unroll
  for (int kb = 0; kb < 32; ++kb) {
    float4 wa = *(const float4*)(Wsrc + kb * 16);
    float4 wb = *(const float4*)(Wsrc + kb * 16 + 4);
    bf16x8 v;
    v[0] = (bf16)wa.x; v[1] = (bf16)wa.y; v[2] = (bf16)wa.z; v[3] = (bf16)wa.w;
    v[4] = (bf16)wb.x; v[5] = (bf16)wb.y; v[6] = (bf16)wb.z; v[7] = (bf16)wb.w;
    bw[kb] = v;
  }
  if (t < 32) {
    const int rr = (t & 3) * 512 + w * 8 + (t >> 2);
    bias[t] = bih[rr] + bhh[rr];
  }
  ldsCnt[t] = 0;
  if (t == 0) ldsCnt0 = 0;
  __syncthreads();

  const int en = t >> 2, ep = t & 3;
  {
    unsigned* Hp = (unsigned*)H + ((size_t)0 * N_ + en) * (C_ / 2) + w * 4 + ep;
    unsigned z = 0;
    asm volatile("global_store_dword %0, %1, off sc0 sc1" :: "v"(Hp), "v"(z) : "memory");
    asm volatile("s_waitcnt vmcnt(0)" ::: "memory");
    if (lane == 0) {
      if (atomicAdd(&ldsCnt0, 1) == 3) {
        int one = 1; int* fp = flags + w;
        asm volatile("global_store_dword %0, %1, off sc0 sc1" :: "v"(fp), "v"(one) : "memory");
      }
    }
  }

  float cs0 = 0.f, cs1 = 0.f;
  const int eb = en >> 5, er = en & 31, j0 = ep * 8;

  bf16x8 xf[32];
  if (mat == 0) {
    const bf16* xb = queue + ((size_t)0 * N_ + blk * 32 + (lane & 31)) * C_ + kg;
#pragma unroll
    for (int kb = 0; kb < 32; ++kb) xf[kb] = *(const bf16x8*)(xb + kb * 16);
    {
      f32x16 acc[4] = {};
#pragma unroll
      for (int kb = 0; kb < 32; ++kb)
        acc[kb & 3] = __builtin_amdgcn_mfma_f32_32x32x16_bf16(xf[kb], bw[kb], acc[kb & 3], 0, 0, 0);
      f32x16 asum = (acc[0] + acc[1]) + (acc[2] + acc[3]);
#pragma unroll
      for (int rg = 0; rg < 16; ++rg) {
        const int rl = (rg & 3) + 8 * (rg >> 2) + 4 * (lane >> 5);
        gx[0][blk][rl][col] = asum[rg];
      }
    }
    const bf16* xb1 = queue + ((size_t)1 * N_ + blk * 32 + (lane & 31)) * C_ + kg;
#pragma unroll
    for (int kb = 0; kb < 32; ++kb) xf[kb] = *(const bf16x8*)(xb1 + kb * 16);
  }

  for (int step = 0; step < Q_; ++step) {
    const int p = step & 1;
    const int cur = p, nxt = p ^ 1;
    if (mat == 1) {
      {
        int v; int* fa = flags + lane;
        do {
          asm volatile("global_load_dword %0, %1, off sc0 sc1" : "=v"(v) : "v"(fa));
          asm volatile("s_waitcnt vmcnt(0)" ::: "memory");
        } while (!__all(v >= step + 1));
      }
      __builtin_amdgcn_sched_barrier(0);
      const bf16* hb = H + ((size_t)cur * N_ + blk * 32 + (lane & 31)) * C_ + kg;
      bf16x8 hf[32];
#pragma unroll
      for (int kb = 0; kb < 32; ++kb)
        asm volatile("global_load_dwordx4 %0, %1, off offset:%2 sc0 sc1"
                     : "=v"(hf[kb]) : "v"(hb), "i"(kb * 32));
      f32x16 acc[4] = {};
      asm volatile("s_waitcnt vmcnt(0)" ::: "memory");
      __builtin_amdgcn_sched_barrier(0);
#pragma unroll
      for (int kb = 0; kb < 32; ++kb)
        acc[kb & 3] = __builtin_amdgcn_mfma_f32_32x32x16_bf16(hf[kb], bw[kb], acc[kb & 3], 0, 0, 0);
      f32x16 asum = (acc[0] + acc[1]) + (acc[2] + acc[3]);
#pragma unroll
      for (int rg = 0; rg < 16; ++rg) {
        const int rl = (rg & 3) + 8 * (rg >> 2) + 4 * (lane >> 5);
        gh[blk][rl][col] = asum[rg];
      }
    } else if (step + 1 < Q_) {
      f32x16 acc[4] = {};
#pragma unroll
      for (int kb = 0; kb < 32; ++kb)
        acc[kb & 3] = __builtin_amdgcn_mfma_f32_32x32x16_bf16(xf[kb], bw[kb], acc[kb & 3], 0, 0, 0);
      f32x16 asum = (acc[0] + acc[1]) + (acc[2] + acc[3]);
#pragma unroll
      for (int rg = 0; rg < 16; ++rg) {
        const int rl = (rg & 3) + 8 * (rg >> 2) + 4 * (lane >> 5);
        gx[p ^ 1][blk][rl][col] = asum[rg];
      }
    }
    __syncthreads();
    {
      float g0 = gx[p][eb][er][j0 + 0] + gh[eb][er][j0 + 0] + bias[j0 + 0];
      float g1 = gx[p][eb][er][j0 + 1] + gh[eb][er][j0 + 1] + bias[j0 + 1];
      float g2 = gx[p][eb][er][j0 + 2] + gh[eb][er][j0 + 2] + bias[j0 + 2];
      float g3 = gx[p][eb][er][j0 + 3] + gh[eb][er][j0 + 3] + bias[j0 + 3];
      cs0 = sigf(g1) * cs0 + sigf(g0) * tanhf_(g2);
      float h0v = sigf(g3) * tanhf_(cs0);
      float g4 = gx[p][eb][er][j0 + 4] + gh[eb][er][j0 + 4] + bias[j0 + 4];
      float g5 = gx[p][eb][er][j0 + 5] + gh[eb][er][j0 + 5] + bias[j0 + 5];
      float g6 = gx[p][eb][er][j0 + 6] + gh[eb][er][j0 + 6] + bias[j0 + 6];
      float g7 = gx[p][eb][er][j0 + 7] + gh[eb][er][j0 + 7] + bias[j0 + 7];
      cs1 = sigf(g5) * cs1 + sigf(g4) * tanhf_(g6);
      float h1v = sigf(g7) * tanhf_(cs1);
      unsigned lo = __builtin_bit_cast(unsigned short, (bf16)h0v);
      unsigned hi = __builtin_bit_cast(unsigned short, (bf16)h1v);
      unsigned hp = (hi << 16) | lo;
      unsigned* Hq = (unsigned*)H + ((size_t)nxt * N_ + en) * (C_ / 2) + w * 4 + ep;
      asm volatile("global_store_dword %0, %1, off sc0 sc1" :: "v"(Hq), "v"(hp) : "memory");
      *((unsigned*)hs + ((size_t)step * N_ + en) * (C_ / 2) + w * 4 + ep) = hp;
    }
    asm volatile("s_waitcnt vmcnt(1)" ::: "memory");
    if (step + 1 < Q_) {
      if (lane == 0) {
        if (atomicAdd(&ldsCnt[step], 1) == 3) {
          int fv = step + 2; int* fp = flags + w;
          asm volatile("global_store_dword %0, %1, off sc0 sc1" :: "v"(fp), "v"(fv) : "memory");
        }
      }
      if (mat == 0 && step + 2 < Q_) {
        const bf16* xb = queue + ((size_t)(step + 2) * N_ + blk * 32 + (lane & 31)) * C_ + kg;
#pragma unroll
        for (int kb = 0; kb < 32; ++kb) xf[kb] = *(const bf16x8*)(xb + kb * 16);
      }
    }
    __syncthreads();
  }
}

// ---------------- stage 5: LayerNorm + decode ----------------
__global__ __launch_bounds__(256) void k_lndec(const bf16* __restrict__ hs,
    const float* __restrict__ gamma, const float* __restrict__ beta,
    const float* __restrict__ Wdec, const float* __restrict__ bdec,
    float* __restrict__ out) {
  const int wid = threadIdx.x >> 6, lane = threadIdx.x & 63;
  const int row = blockIdx.x * 4 + wid;
  const bf16* hrow = hs + (size_t)row * C_ + lane * 8;
  bf16x8 hv = *(const bf16x8*)hrow;
  float h[8];
  float sm = 0.f, sq = 0.f;
#pragma unroll
  for (int j = 0; j < 8; ++j) {
    h[j] = (float)hv[j];
    sm += h[j];
    sq += h[j] * h[j];
  }
#pragma unroll
  for (int m = 32; m >= 1; m >>= 1) {
    sm += __shfl_xor(sm, m);
    sq += __shfl_xor(sq, m);
  }
  const float mu = sm * (1.f / C_);
  const float var = sq * (1.f / C_) - mu * mu;
  const float rs = 1.f / sqrtf(var + 1e-5f);
  float o[V_] = {};
#pragma unroll
  for (int j = 0; j < 8; ++j) {
    const int cj = lane * 8 + j;
    const float nv = (h[j] - mu) * rs * gamma[cj] + beta[cj];
    const float* wr = Wdec + (size_t)cj * V_;
#pragma unroll
    for (int v = 0; v < V_; ++v) o[v] += nv * wr[v];
  }
#pragma unroll
  for (int v = 0; v < V_; ++v) {
#pragma unroll
    for (int m = 32; m >= 1; m >>= 1) o[v] += __shfl_xor(o[v], m);
  }
  if (lane == 0) {
#pragma unroll
    for (int v = 0; v < V_; ++v) out[(size_t)row * V_ + v] = o[v] + bdec[v];
  }
}

extern "C" void kernel_launch(void* const* d_in, const int* in_sizes, int n_in,
                              void* d_out, int out_size, void* d_ws, size_t ws_size,
                              hipStream_t stream) {
  (void)in_sizes; (void)n_in; (void)out_size;
  const float* mem  = (const float*)d_in[0];
  const float* Wact = (const float*)d_in[1];
  const float* bact = (const float*)d_in[2];
  const float* Wih  = (const float*)d_in[3];
  const float* Whh  = (const float*)d_in[4];
  const float* bih  = (const float*)d_in[5];
  const float* bhh  = (const float*)d_in[6];
  const float* gam  = (const float*)d_in[7];
  const float* bet  = (const float*)d_in[8];
  const float* Wdec = (const float*)d_in[9];
  const float* bdec = (const float*)d_in[10];
  float* out = (float*)d_out;
  char* ws = (char*)d_ws;

  if (ws_size >= OFF_END) {
    float* A0    = (float*)(ws + OFF_A0);
    float* A1    = (float*)(ws + OFF_A1);
    bf16* qu     = (bf16*)(ws + OFF_QU);
    unsigned* Hg = (unsigned*)(ws + OFF_HGU);
    bf16* Hfb    = (bf16*)(ws + OFF_HFB);
    int* ctrl    = (int*)(ws + OFF_CTRL);
    bf16* hs     = (bf16*)(ws + OFF_HS);
    bf16* Wb     = (bf16*)(ws + OFF_WB);
    bf16* Pw     = (bf16*)(ws + OFF_PW);
    bf16* GX     = (bf16*)(ws + OFF_GX);

    hipMemsetAsync(ctrl, 0, 4096, stream);
    k_actions<<<(S_ * N_) / 4, 256, 0, stream>>>(mem, Wact, bact, A0, A1);
    k_posvec<<<N_, 256, 0, stream>>>(A0, A1, Pw);
    k_queue<<<N_ * 32, 256, 0, stream>>>(Pw, mem, qu);
    k_cvtw<<<1024, 256, 0, stream>>>(Wih, Whh, Wb);
    k_gx<<<8192, 256, 0, stream>>>(qu, Wb, bih, bhh, GX);
    k_rec<<<128, 256, 0, stream>>>(Wb, GX, Hg, hs, ctrl);
    k_lstm_fb<<<64, 256, 0, stream>>>(qu, Wih, Whh, bih, bhh, Hfb, hs, ctrl, 0);
    k_lndec<<<(Q_ * N_) / 4, 256, 0, stream>>>(hs, gam, bet, Wdec, bdec, out);
  } else {
    float* A0 = (float*)(ws + FB_A0);
    float* A1 = (float*)(ws + FB_A1);
    bf16* Pw  = (bf16*)(ws + FB_PW);
    bf16* qu  = (bf16*)(ws + FB_QU);
    bf16* H   = (bf16*)(ws + FB_H);
    bf16* hs  = (bf16*)(ws + FB_HS);
    int* ctrl = (int*)(ws + FB_BAR);

    hipMemsetAsync(ctrl, 0, 4096, stream);
    k_actions<<<(S_ * N_) / 4, 256, 0, stream>>>(mem, Wact, bact, A0, A1);
    k_posvec<<<N_, 256, 0, stream>>>(A0, A1, Pw);
    k_queue<<<N_ * 32, 256, 0, stream>>>(Pw, mem, qu);
    k_lstm_fb<<<64, 256, 0, stream>>>(qu, Wih, Whh, bih, bhh, H, hs, ctrl, 1);
    k_lndec<<<(Q_ * N_) / 4, 256, 0, stream>>>(hs, gam, bet, Wdec, bdec, out);
  }
}

// Round 8
// 2194.162 us; speedup vs baseline: 22.3173x; 22.3173x over previous
//
#include <hip/hip_runtime.h>
#include <hip/hip_bf16.h>

typedef __bf16 bf16;
typedef __bf16 bf16x8 __attribute__((ext_vector_type(8)));
typedef float f32x4 __attribute__((ext_vector_type(4)));
typedef float f32x16 __attribute__((ext_vector_type(16)));

#define S_ 512
#define N_ 64
#define C_ 512
#define V_ 10
#define Q_ 256

// ---- workspace layout (bytes) ----
#define OFF_A0   ((size_t)0)
#define OFF_A1   (OFF_A0 + (size_t)S_ * N_ * 4)
#define OFF_PW   (OFF_A1 + (size_t)S_ * N_ * 4)            // bf16 [N][Q][S]
#define OFF_QU   (OFF_PW + (size_t)N_ * Q_ * S_ * 2)       // bf16 [Q][N][C]
#define OFF_HSEQ (OFF_QU + (size_t)Q_ * N_ * C_ * 2)       // bf16 [Q][N][C] (perm'd step rows)
#define OFF_HS   (OFF_HSEQ + (size_t)Q_ * N_ * C_ * 2)     // bf16 [Q][N][C] (ordered, for lndec)
#define OFF_CTRL (OFF_HS + (size_t)Q_ * N_ * C_ * 2)       // int flags[64] at +64

__device__ __forceinline__ float sigf(float x) { return 1.f / (1.f + __expf(-x)); }
__device__ __forceinline__ float tanhf_(float x) { return 1.f - 2.f / (__expf(2.f * x) + 1.f); }

// ---------------- stage 1: action softmax ----------------
__global__ __launch_bounds__(256) void k_actions(const float* __restrict__ mem,
    const float* __restrict__ Wact, const float* __restrict__ bact,
    float* __restrict__ A0, float* __restrict__ A1) {
  const int wid = threadIdx.x >> 6, lane = threadIdx.x & 63;
  const int row = blockIdx.x * 4 + wid;          // row = s*64 + n
  const int s = row >> 6, n = row & 63;
  const float* mrow = mem + (size_t)row * C_ + lane * 8;
  const float* wrow = Wact + (size_t)lane * 16;
  float4 m0 = *(const float4*)(mrow);
  float4 m1 = *(const float4*)(mrow + 4);
  float d0 = 0.f, d1 = 0.f;
  float mv[8] = {m0.x, m0.y, m0.z, m0.w, m1.x, m1.y, m1.z, m1.w};
#pragma unroll
  for (int j = 0; j < 8; ++j) {
    d0 += mv[j] * wrow[j * 2 + 0];
    d1 += mv[j] * wrow[j * 2 + 1];
  }
#pragma unroll
  for (int m = 32; m >= 1; m >>= 1) {
    d0 += __shfl_xor(d0, m);
    d1 += __shfl_xor(d1, m);
  }
  if (lane == 0) {
    float l0 = d0 + bact[0], l1 = d1 + bact[1];
    float mx = fmaxf(l0, l1);
    float e0 = __expf(l0 - mx), e1 = __expf(l1 - mx);
    float inv = 1.f / (e0 + e1);
    A0[(size_t)n * S_ + s] = e0 * inv;
    A1[(size_t)n * S_ + s] = e1 * inv;
  }
}

// ---------------- stage 2: posvec scan ----------------
__global__ __launch_bounds__(256) void k_posvec(const float* __restrict__ A0,
    const float* __restrict__ A1, bf16* __restrict__ Pw) {
  __shared__ float a0s[S_], a1s[S_];
  __shared__ float pbuf[2][Q_];
  const int n = blockIdx.x, t = threadIdx.x;
  a0s[t] = A0[(size_t)n * S_ + t];
  a0s[t + 256] = A0[(size_t)n * S_ + t + 256];
  a1s[t] = A1[(size_t)n * S_ + t];
  a1s[t + 256] = A1[(size_t)n * S_ + t + 256];
  float p = (t == 0) ? 1.f : 0.f;
  __syncthreads();
  for (int s8 = 0; s8 < S_; s8 += 8) {
    float emit[8];
#pragma unroll
    for (int jj = 0; jj < 8; ++jj) {
      const int s = s8 + jj;
      pbuf[jj & 1][t] = p;
      __syncthreads();
      float pm1 = pbuf[jj & 1][(t + Q_ - 1) & (Q_ - 1)];
      float a0 = a0s[s], a1 = a1s[s];
      emit[jj] = p * a1;
      p = fmaf(pm1, a1, p * a0);
    }
    bf16x8 v;
#pragma unroll
    for (int jj = 0; jj < 8; ++jj) v[jj] = (bf16)emit[jj];
    *(bf16x8*)(Pw + ((size_t)n * Q_ + t) * S_ + s8) = v;
  }
}

// ---------------- stage 3: queue einsum ----------------
__global__ __launch_bounds__(256) void k_queue(const bf16* __restrict__ Pw,
    const float* __restrict__ mem, bf16* __restrict__ qout) {
  __shared__ bf16 bt[64 * 32];
  const int bid = blockIdx.x;
  const int n = bid >> 5, qt = (bid >> 3) & 3, ct = bid & 7;
  const int q0 = qt * 64, c0 = ct * 64;
  const int t = threadIdx.x, wid = t >> 6, lane = t & 63;
  const int lrow = lane & 15, lkb = lane >> 4;
  f32x4 acc[4] = {};
  const bf16* arow = Pw + ((size_t)n * Q_ + q0 + wid * 16 + lrow) * S_ + lkb * 8;
  const int sl = t >> 3, cb = (t & 7) * 8;
  const float* msrc = mem + ((size_t)sl * N_ + n) * C_ + c0 + cb;
  for (int kb = 0; kb < 16; ++kb) {
    float4 f0 = *(const float4*)(msrc + (size_t)kb * 32 * N_ * C_);
    float4 f1 = *(const float4*)(msrc + (size_t)kb * 32 * N_ * C_ + 4);
    __syncthreads();
    float fv[8] = {f0.x, f0.y, f0.z, f0.w, f1.x, f1.y, f1.z, f1.w};
#pragma unroll
    for (int jw = 0; jw < 8; ++jw) {
      const int row = cb + jw;
      bt[row * 32 + ((((sl >> 3) ^ (row & 3)) << 3) | (sl & 7))] = (bf16)fv[jw];
    }
    __syncthreads();
    bf16x8 a = *(const bf16x8*)(arow + kb * 32);
#pragma unroll
    for (int cs = 0; cs < 4; ++cs) {
      const int row = cs * 16 + lrow;
      bf16x8 b = *(const bf16x8*)(&bt[row * 32 + ((lkb ^ (row & 3)) << 3)]);
      acc[cs] = __builtin_amdgcn_mfma_f32_16x16x32_bf16(a, b, acc[cs], 0, 0, 0);
    }
  }
#pragma unroll
  for (int cs = 0; cs < 4; ++cs) {
#pragma unroll
    for (int r = 0; r < 4; ++r) {
      const int q = q0 + wid * 16 + (lane >> 4) * 4 + r;
      const int c = c0 + cs * 16 + lrow;
      qout[((size_t)q * N_ + n) * C_ + c] = (bf16)acc[cs][r];
    }
  }
}

// ---------------- stage 4: LSTM (64 WGs, LLC flags + cached cold-read h) ----------------
// h_t published to Hseq[perm(t)] (sc0 sc1 -> LLC); consumers read with PLAIN loads:
// address cold in reader L2 (write-once/read-once, perm keeps steps 6MB apart) -> miss
// -> LLC -> fresh, via the fast cached path. Only wave 2 polls flags (s_sleep backoff).
__global__ __launch_bounds__(256, 1) void k_lstm(
    const bf16* __restrict__ queue, const float* __restrict__ Wih,
    const float* __restrict__ Whh, const float* __restrict__ bih,
    const float* __restrict__ bhh, bf16* __restrict__ Hseq,
    bf16* __restrict__ hs, int* __restrict__ ctrl) {
  __shared__ float gx[2][2][32][33];  // [step parity][Mblk][row][col]
  __shared__ float gh[2][32][33];     // [Mblk][row][col]
  __shared__ float bias[32];
  __shared__ int ldsCnt[Q_];
  int* flags = ctrl + 64;
  const int w = blockIdx.x, t = threadIdx.x;
  const int wid = t >> 6, lane = t & 63;
  const int mat = wid >> 1;   // 0 = x (W_ih), 1 = h (W_hh)
  const int blk = wid & 1;    // n-rows blk*32 .. +32

  // weight B-fragments -> registers (held across all steps)
  const int col = lane & 31;                 // gate col j: gate=j&3, ch=w*8+(j>>2)
  const int kg = (lane >> 5) * 8;
  const int wr = (col & 3) * 512 + w * 8 + (col >> 2);
  const float* Wsrc = (mat ? Whh : Wih) + (size_t)wr * C_ + kg;
  bf16x8 bw[32];
#pragma unroll
  for (int kb = 0; kb < 32; ++kb) {
    float4 wa = *(const float4*)(Wsrc + kb * 16);
    float4 wb = *(const float4*)(Wsrc + kb * 16 + 4);
    bf16x8 v;
    v[0] = (bf16)wa.x; v[1] = (bf16)wa.y; v[2] = (bf16)wa.z; v[3] = (bf16)wa.w;
    v[4] = (bf16)wb.x; v[5] = (bf16)wb.y; v[6] = (bf16)wb.z; v[7] = (bf16)wb.w;
    bw[kb] = v;
  }
  if (t < 32) {
    const int rr = (t & 3) * 512 + w * 8 + (t >> 2);
    bias[t] = bih[rr] + bhh[rr];
  }
  ldsCnt[t] = 0;
  __syncthreads();

  float cs0 = 0.f, cs1 = 0.f;
  const int en = t >> 2, ep = t & 3;         // elementwise: n=en, channels w*8+2ep,+1
  const int eb = en >> 5, er = en & 31, j0 = ep * 8;

  bf16x8 xf[32];  // x A-fragments (holds x(step+1) at loop top)
  if (mat == 0) {
    const bf16* xb = queue + ((size_t)0 * N_ + blk * 32 + (lane & 31)) * C_ + kg;
#pragma unroll
    for (int kb = 0; kb < 32; ++kb) xf[kb] = *(const bf16x8*)(xb + kb * 16);
    {  // gx for step 0
      f32x16 acc[4] = {};
#pragma unroll
      for (int kb = 0; kb < 32; ++kb)
        acc[kb & 3] = __builtin_amdgcn_mfma_f32_32x32x16_bf16(xf[kb], bw[kb], acc[kb & 3], 0, 0, 0);
      f32x16 asum = (acc[0] + acc[1]) + (acc[2] + acc[3]);
#pragma unroll
      for (int rg = 0; rg < 16; ++rg) {
        const int rl = (rg & 3) + 8 * (rg >> 2) + 4 * (lane >> 5);
        gx[0][blk][rl][col] = asum[rg];
      }
    }
    const bf16* xb1 = queue + ((size_t)1 * N_ + blk * 32 + (lane & 31)) * C_ + kg;
#pragma unroll
    for (int kb = 0; kb < 32; ++kb) xf[kb] = *(const bf16x8*)(xb1 + kb * 16);
  }

  for (int step = 0; step < Q_; ++step) {
    const int p = step & 1;
    // ---- wave 2 polls flags for hs(step-1) completion; backoff to decongest LLC ----
    if (wid == 2 && step > 0) {
      int v;
      int* fa = flags + lane;
      while (true) {
        asm volatile("global_load_dword %0, %1, off sc0 sc1" : "=v"(v) : "v"(fa));
        asm volatile("s_waitcnt vmcnt(0)" ::: "memory");
        if (__all(v >= step)) break;
        __builtin_amdgcn_s_sleep(1);
      }
    }
    __syncthreads();  // S0: h(step-1) published (flags verified by wave 2)

    if (mat == 1) {
      // ---- h-part: plain cached loads from cold Hseq[perm(step-1)] rows ----
      f32x16 acc[4] = {};
      if (step > 0) {
        const int sp = ((step - 1) * 97) & 255;
        const bf16* hrow = Hseq + ((size_t)sp * N_ + blk * 32 + (lane & 31)) * C_ + kg;
#pragma unroll
        for (int c8 = 0; c8 < 4; ++c8) {
          bf16x8 hf[8];
#pragma unroll
          for (int kk = 0; kk < 8; ++kk) hf[kk] = *(const bf16x8*)(hrow + (c8 * 8 + kk) * 16);
#pragma unroll
          for (int kk = 0; kk < 8; ++kk) {
            const int kb = c8 * 8 + kk;
            acc[kb & 3] = __builtin_amdgcn_mfma_f32_32x32x16_bf16(hf[kk], bw[kb], acc[kb & 3], 0, 0, 0);
          }
        }
      }
      f32x16 asum = (acc[0] + acc[1]) + (acc[2] + acc[3]);
#pragma unroll
      for (int rg = 0; rg < 16; ++rg) {
        const int rl = (rg & 3) + 8 * (rg >> 2) + 4 * (lane >> 5);
        gh[blk][rl][col] = asum[rg];
      }
    } else if (step + 1 < Q_) {
      // ---- x-waves: gates for step+1 from prefetched xf ----
      f32x16 acc[4] = {};
#pragma unroll
      for (int kb = 0; kb < 32; ++kb)
        acc[kb & 3] = __builtin_amdgcn_mfma_f32_32x32x16_bf16(xf[kb], bw[kb], acc[kb & 3], 0, 0, 0);
      f32x16 asum = (acc[0] + acc[1]) + (acc[2] + acc[3]);
#pragma unroll
      for (int rg = 0; rg < 16; ++rg) {
        const int rl = (rg & 3) + 8 * (rg >> 2) + 4 * (lane >> 5);
        gx[p ^ 1][blk][rl][col] = asum[rg];
      }
    }
    __syncthreads();  // S1: gh + gx[p] ready

    {  // elementwise: n=en, channels w*8+2ep,+1; c-state in registers
      float g0 = gx[p][eb][er][j0 + 0] + gh[eb][er][j0 + 0] + bias[j0 + 0];
      float g1 = gx[p][eb][er][j0 + 1] + gh[eb][er][j0 + 1] + bias[j0 + 1];
      float g2 = gx[p][eb][er][j0 + 2] + gh[eb][er][j0 + 2] + bias[j0 + 2];
      float g3 = gx[p][eb][er][j0 + 3] + gh[eb][er][j0 + 3] + bias[j0 + 3];
      cs0 = sigf(g1) * cs0 + sigf(g0) * tanhf_(g2);
      float h0v = sigf(g3) * tanhf_(cs0);
      float g4 = gx[p][eb][er][j0 + 4] + gh[eb][er][j0 + 4] + bias[j0 + 4];
      float g5 = gx[p][eb][er][j0 + 5] + gh[eb][er][j0 + 5] + bias[j0 + 5];
      float g6 = gx[p][eb][er][j0 + 6] + gh[eb][er][j0 + 6] + bias[j0 + 6];
      float g7 = gx[p][eb][er][j0 + 7] + gh[eb][er][j0 + 7] + bias[j0 + 7];
      cs1 = sigf(g5) * cs1 + sigf(g4) * tanhf_(g6);
      float h1v = sigf(g7) * tanhf_(cs1);
      unsigned lo = (unsigned)__builtin_bit_cast(unsigned short, (bf16)h0v);
      unsigned hi = (unsigned)__builtin_bit_cast(unsigned short, (bf16)h1v);
      unsigned hp = (hi << 16) | lo;
      const int spw = (step * 97) & 255;   // perm'd publish row
      unsigned* Hq = (unsigned*)Hseq + ((size_t)spw * N_ + en) * (C_ / 2) + w * 4 + ep;
      asm volatile("global_store_dword %0, %1, off sc0 sc1" :: "v"(Hq), "v"(hp) : "memory");
      *((unsigned*)hs + ((size_t)step * N_ + en) * (C_ / 2) + w * 4 + ep) = hp;
    }
    asm volatile("s_waitcnt vmcnt(0)" ::: "memory");  // h at LLC before flag
    if (step + 1 < Q_) {
      if (lane == 0) {
        if (atomicAdd(&ldsCnt[step], 1) == 3) {  // last wave of this WG
          int fv = step + 1;
          int* fp = flags + w;
          asm volatile("global_store_dword %0, %1, off sc0 sc1" :: "v"(fp), "v"(fv) : "memory");
        }
      }
      if (mat == 0 && step + 2 < Q_) {  // prefetch x(step+2)
        const bf16* xb = queue + ((size_t)(step + 2) * N_ + blk * 32 + (lane & 31)) * C_ + kg;
#pragma unroll
        for (int kb = 0; kb < 32; ++kb) xf[kb] = *(const bf16x8*)(xb + kb * 16);
      }
    }
    __syncthreads();  // S2: fences gx parity reuse / ldsCnt
  }
}

// ---------------- stage 5: LayerNorm + decode ----------------
__global__ __launch_bounds__(256) void k_lndec(const bf16* __restrict__ hs,
    const float* __restrict__ gamma, const float* __restrict__ beta,
    const float* __restrict__ Wdec, const float* __restrict__ bdec,
    float* __restrict__ out) {
  const int wid = threadIdx.x >> 6, lane = threadIdx.x & 63;
  const int row = blockIdx.x * 4 + wid;
  const bf16* hrow = hs + (size_t)row * C_ + lane * 8;
  bf16x8 hv = *(const bf16x8*)hrow;
  float h[8];
  float sm = 0.f, sq = 0.f;
#pragma unroll
  for (int j = 0; j < 8; ++j) {
    h[j] = (float)hv[j];
    sm += h[j];
    sq += h[j] * h[j];
  }
#pragma unroll
  for (int m = 32; m >= 1; m >>= 1) {
    sm += __shfl_xor(sm, m);
    sq += __shfl_xor(sq, m);
  }
  const float mu = sm * (1.f / C_);
  const float var = sq * (1.f / C_) - mu * mu;
  const float rs = 1.f / sqrtf(var + 1e-5f);
  float o[V_] = {};
#pragma unroll
  for (int j = 0; j < 8; ++j) {
    const int cj = lane * 8 + j;
    const float nv = (h[j] - mu) * rs * gamma[cj] + beta[cj];
    const float* wr = Wdec + (size_t)cj * V_;
#pragma unroll
    for (int v = 0; v < V_; ++v) o[v] += nv * wr[v];
  }
#pragma unroll
  for (int v = 0; v < V_; ++v) {
#pragma unroll
    for (int m = 32; m >= 1; m >>= 1) o[v] += __shfl_xor(o[v], m);
  }
  if (lane == 0) {
#pragma unroll
    for (int v = 0; v < V_; ++v) out[(size_t)row * V_ + v] = o[v] + bdec[v];
  }
}

extern "C" void kernel_launch(void* const* d_in, const int* in_sizes, int n_in,
                              void* d_out, int out_size, void* d_ws, size_t ws_size,
                              hipStream_t stream) {
  (void)in_sizes; (void)n_in; (void)out_size; (void)ws_size;
  const float* mem  = (const float*)d_in[0];
  const float* Wact = (const float*)d_in[1];
  const float* bact = (const float*)d_in[2];
  const float* Wih  = (const float*)d_in[3];
  const float* Whh  = (const float*)d_in[4];
  const float* bih  = (const float*)d_in[5];
  const float* bhh  = (const float*)d_in[6];
  const float* gam  = (const float*)d_in[7];
  const float* bet  = (const float*)d_in[8];
  const float* Wdec = (const float*)d_in[9];
  const float* bdec = (const float*)d_in[10];
  float* out = (float*)d_out;

  char* ws = (char*)d_ws;
  float* A0  = (float*)(ws + OFF_A0);
  float* A1  = (float*)(ws + OFF_A1);
  bf16* Pw   = (bf16*)(ws + OFF_PW);
  bf16* qu   = (bf16*)(ws + OFF_QU);
  bf16* Hsq  = (bf16*)(ws + OFF_HSEQ);
  bf16* hs   = (bf16*)(ws + OFF_HS);
  int* ctrl  = (int*)(ws + OFF_CTRL);

  hipMemsetAsync(ctrl, 0, 4096, stream);
  k_actions<<<(S_ * N_) / 4, 256, 0, stream>>>(mem, Wact, bact, A0, A1);
  k_posvec<<<N_, 256, 0, stream>>>(A0, A1, Pw);
  k_queue<<<N_ * 32, 256, 0, stream>>>(Pw, mem, qu);
  k_lstm<<<64, 256, 0, stream>>>(qu, Wih, Whh, bih, bhh, Hsq, hs, ctrl);
  k_lndec<<<(Q_ * N_) / 4, 256, 0, stream>>>(hs, gam, bet, Wdec, bdec, out);
}

// Round 9
// 2061.943 us; speedup vs baseline: 23.7484x; 1.0641x over previous
//
#include <hip/hip_runtime.h>
#include <hip/hip_bf16.h>

typedef __bf16 bf16;
typedef __bf16 bf16x8 __attribute__((ext_vector_type(8)));
typedef float f32x4 __attribute__((ext_vector_type(4)));
typedef float f32x16 __attribute__((ext_vector_type(16)));

#define S_ 512
#define N_ 64
#define C_ 512
#define V_ 10
#define Q_ 256

// ---- workspace layout (bytes) ----
#define OFF_A0   ((size_t)0)
#define OFF_A1   (OFF_A0 + (size_t)S_ * N_ * 4)
#define OFF_PW   (OFF_A1 + (size_t)S_ * N_ * 4)            // bf16 [N][Q][S]
#define OFF_QU   (OFF_PW + (size_t)N_ * Q_ * S_ * 2)       // bf16 [Q][N][C]
#define OFF_HP   (OFF_QU + (size_t)Q_ * N_ * C_ * 2)       // u32 [2][N][C] tagged h
#define OFF_HS   (OFF_HP + (size_t)2 * N_ * C_ * 4)        // bf16 [Q][N][C]
#define OFF_CTRL (OFF_HS + (size_t)Q_ * N_ * C_ * 2)       // int flags[64] at +64

__device__ __forceinline__ float sigf(float x) { return 1.f / (1.f + __expf(-x)); }
__device__ __forceinline__ float tanhf_(float x) { return 1.f - 2.f / (__expf(2.f * x) + 1.f); }

// ---------------- stage 1: action softmax ----------------
__global__ __launch_bounds__(256) void k_actions(const float* __restrict__ mem,
    const float* __restrict__ Wact, const float* __restrict__ bact,
    float* __restrict__ A0, float* __restrict__ A1) {
  const int wid = threadIdx.x >> 6, lane = threadIdx.x & 63;
  const int row = blockIdx.x * 4 + wid;          // row = s*64 + n
  const int s = row >> 6, n = row & 63;
  const float* mrow = mem + (size_t)row * C_ + lane * 8;
  const float* wrow = Wact + (size_t)lane * 16;
  float4 m0 = *(const float4*)(mrow);
  float4 m1 = *(const float4*)(mrow + 4);
  float d0 = 0.f, d1 = 0.f;
  float mv[8] = {m0.x, m0.y, m0.z, m0.w, m1.x, m1.y, m1.z, m1.w};
#pragma unroll
  for (int j = 0; j < 8; ++j) {
    d0 += mv[j] * wrow[j * 2 + 0];
    d1 += mv[j] * wrow[j * 2 + 1];
  }
#pragma unroll
  for (int m = 32; m >= 1; m >>= 1) {
    d0 += __shfl_xor(d0, m);
    d1 += __shfl_xor(d1, m);
  }
  if (lane == 0) {
    float l0 = d0 + bact[0], l1 = d1 + bact[1];
    float mx = fmaxf(l0, l1);
    float e0 = __expf(l0 - mx), e1 = __expf(l1 - mx);
    float inv = 1.f / (e0 + e1);
    A0[(size_t)n * S_ + s] = e0 * inv;
    A1[(size_t)n * S_ + s] = e1 * inv;
  }
}

// ---------------- stage 2: posvec scan ----------------
__global__ __launch_bounds__(256) void k_posvec(const float* __restrict__ A0,
    const float* __restrict__ A1, bf16* __restrict__ Pw) {
  __shared__ float a0s[S_], a1s[S_];
  __shared__ float pbuf[2][Q_];
  const int n = blockIdx.x, t = threadIdx.x;
  a0s[t] = A0[(size_t)n * S_ + t];
  a0s[t + 256] = A0[(size_t)n * S_ + t + 256];
  a1s[t] = A1[(size_t)n * S_ + t];
  a1s[t + 256] = A1[(size_t)n * S_ + t + 256];
  float p = (t == 0) ? 1.f : 0.f;
  __syncthreads();
  for (int s8 = 0; s8 < S_; s8 += 8) {
    float emit[8];
#pragma unroll
    for (int jj = 0; jj < 8; ++jj) {
      const int s = s8 + jj;
      pbuf[jj & 1][t] = p;
      __syncthreads();
      float pm1 = pbuf[jj & 1][(t + Q_ - 1) & (Q_ - 1)];
      float a0 = a0s[s], a1 = a1s[s];
      emit[jj] = p * a1;
      p = fmaf(pm1, a1, p * a0);
    }
    bf16x8 v;
#pragma unroll
    for (int jj = 0; jj < 8; ++jj) v[jj] = (bf16)emit[jj];
    *(bf16x8*)(Pw + ((size_t)n * Q_ + t) * S_ + s8) = v;
  }
}

// ---------------- stage 3: queue einsum ----------------
__global__ __launch_bounds__(256) void k_queue(const bf16* __restrict__ Pw,
    const float* __restrict__ mem, bf16* __restrict__ qout) {
  __shared__ bf16 bt[64 * 32];
  const int bid = blockIdx.x;
  const int n = bid >> 5, qt = (bid >> 3) & 3, ct = bid & 7;
  const int q0 = qt * 64, c0 = ct * 64;
  const int t = threadIdx.x, wid = t >> 6, lane = t & 63;
  const int lrow = lane & 15, lkb = lane >> 4;
  f32x4 acc[4] = {};
  const bf16* arow = Pw + ((size_t)n * Q_ + q0 + wid * 16 + lrow) * S_ + lkb * 8;
  const int sl = t >> 3, cb = (t & 7) * 8;
  const float* msrc = mem + ((size_t)sl * N_ + n) * C_ + c0 + cb;
  for (int kb = 0; kb < 16; ++kb) {
    float4 f0 = *(const float4*)(msrc + (size_t)kb * 32 * N_ * C_);
    float4 f1 = *(const float4*)(msrc + (size_t)kb * 32 * N_ * C_ + 4);
    __syncthreads();
    float fv[8] = {f0.x, f0.y, f0.z, f0.w, f1.x, f1.y, f1.z, f1.w};
#pragma unroll
    for (int jw = 0; jw < 8; ++jw) {
      const int row = cb + jw;
      bt[row * 32 + ((((sl >> 3) ^ (row & 3)) << 3) | (sl & 7))] = (bf16)fv[jw];
    }
    __syncthreads();
    bf16x8 a = *(const bf16x8*)(arow + kb * 32);
#pragma unroll
    for (int cs = 0; cs < 4; ++cs) {
      const int row = cs * 16 + lrow;
      bf16x8 b = *(const bf16x8*)(&bt[row * 32 + ((lkb ^ (row & 3)) << 3)]);
      acc[cs] = __builtin_amdgcn_mfma_f32_16x16x32_bf16(a, b, acc[cs], 0, 0, 0);
    }
  }
#pragma unroll
  for (int cs = 0; cs < 4; ++cs) {
#pragma unroll
    for (int r = 0; r < 4; ++r) {
      const int q = q0 + wid * 16 + (lane >> 4) * 4 + r;
      const int c = c0 + cs * 16 + lrow;
      qout[((size_t)q * N_ + n) * C_ + c] = (bf16)acc[cs][r];
    }
  }
}

// ---------------- stage 4: LSTM (R4 backbone + tagged h, no producer drain, no S2) ----------------
// Hp word = (tag<<16)|bf16(h), tag = consuming step. Producer: store h (sc0 sc1), no
// drain, then flag. Consumer: poll flags (gates retry storms), tagged chunked load
// + verify + rare retry. gx triple-buffered, gh parity-buffered -> single barrier/step.

#define ISSUE_CH(BUF, C8)                                                        \
  {                                                                              \
    _Pragma("unroll") for (int i_ = 0; i_ < 8; ++i_)                             \
        asm volatile("global_load_dwordx4 %0, %1, off offset:%2 sc0 sc1"         \
                     : "=v"(BUF[i_])                                             \
                     : "v"(hb), "i"((C8) * 256 + (i_ >> 1) * 64 + (i_ & 1) * 16)); \
  }

#define CHECK_CH(BUF, OKV)                                                       \
  {                                                                              \
    unsigned a_ = 0;                                                             \
    _Pragma("unroll") for (int i_ = 0; i_ < 8; ++i_) {                           \
      a_ |= (BUF[i_].x ^ want); a_ |= (BUF[i_].y ^ want);                        \
      a_ |= (BUF[i_].z ^ want); a_ |= (BUF[i_].w ^ want);                        \
    }                                                                            \
    OKV = (a_ < 0x10000u);                                                       \
  }

#define CONSUME_CH(BUF, C8)                                                      \
  {                                                                              \
    _Pragma("unroll") for (int k_ = 0; k_ < 4; ++k_) {                           \
      union { unsigned u[4]; bf16x8 v; } cv_;                                    \
      cv_.u[0] = (BUF[k_ * 2].y << 16) | (BUF[k_ * 2].x & 0xffffu);              \
      cv_.u[1] = (BUF[k_ * 2].w << 16) | (BUF[k_ * 2].z & 0xffffu);              \
      cv_.u[2] = (BUF[k_ * 2 + 1].y << 16) | (BUF[k_ * 2 + 1].x & 0xffffu);      \
      cv_.u[3] = (BUF[k_ * 2 + 1].w << 16) | (BUF[k_ * 2 + 1].z & 0xffffu);      \
      const int kb_ = (C8) * 4 + k_;                                             \
      acc[kb_ & 1] = __builtin_amdgcn_mfma_f32_32x32x16_bf16(cv_.v, bw[kb_],     \
                                                             acc[kb_ & 1], 0, 0, 0); \
    }                                                                            \
  }

#define CH_STEP(C8, X, Y)                                                        \
  {                                                                              \
    if ((C8) < 7) {                                                              \
      ISSUE_CH(Y, (C8) + 1);                                                     \
      asm volatile("s_waitcnt vmcnt(8)" ::: "memory");                           \
    } else {                                                                     \
      asm volatile("s_waitcnt vmcnt(0)" ::: "memory");                           \
    }                                                                            \
    __builtin_amdgcn_sched_barrier(0);                                           \
    int ok_;                                                                     \
    CHECK_CH(X, ok_);                                                            \
    while (!__all(ok_)) {                                                        \
      ISSUE_CH(X, C8);                                                           \
      asm volatile("s_waitcnt vmcnt(0)" ::: "memory");                           \
      __builtin_amdgcn_sched_barrier(0);                                         \
      CHECK_CH(X, ok_);                                                          \
    }                                                                            \
    CONSUME_CH(X, C8)                                                            \
  }

__global__ __launch_bounds__(256, 1) void k_lstm(
    const bf16* __restrict__ queue, const float* __restrict__ Wih,
    const float* __restrict__ Whh, const float* __restrict__ bih,
    const float* __restrict__ bhh, unsigned* __restrict__ Hp,
    bf16* __restrict__ hs, int* __restrict__ ctrl) {
  __shared__ float gx[3][2][32][33];  // [step%3][Mblk][row][col]
  __shared__ float gh[2][2][32][33];  // [step&1][Mblk][row][col]
  __shared__ float bias[32];
  __shared__ int ldsCnt[Q_];
  int* flags = ctrl + 64;
  const int w = blockIdx.x, t = threadIdx.x;
  const int wid = t >> 6, lane = t & 63;
  const int mat = wid >> 1;   // 0 = x (W_ih), 1 = h (W_hh)
  const int blk = wid & 1;    // n-rows blk*32 .. +32

  // weight B-fragments -> registers (held across all steps)
  const int col = lane & 31;                 // gate col j: gate=j&3, ch=w*8+(j>>2)
  const int kg = (lane >> 5) * 8;
  const int wr = (col & 3) * 512 + w * 8 + (col >> 2);
  const float* Wsrc = (mat ? Whh : Wih) + (size_t)wr * C_ + kg;
  bf16x8 bw[32];
#pragma unroll
  for (int kb = 0; kb < 32; ++kb) {
    float4 wa = *(const float4*)(Wsrc + kb * 16);
    float4 wb = *(const float4*)(Wsrc + kb * 16 + 4);
    bf16x8 v;
    v[0] = (bf16)wa.x; v[1] = (bf16)wa.y; v[2] = (bf16)wa.z; v[3] = (bf16)wa.w;
    v[4] = (bf16)wb.x; v[5] = (bf16)wb.y; v[6] = (bf16)wb.z; v[7] = (bf16)wb.w;
    bw[kb] = v;
  }
  if (t < 32) {
    const int rr = (t & 3) * 512 + w * 8 + (t >> 2);
    bias[t] = bih[rr] + bhh[rr];
  }
  ldsCnt[t] = 0;
  __syncthreads();

  float cs0 = 0.f, cs1 = 0.f;
  const int en = t >> 2, ep = t & 3;         // elementwise: n=en, channels w*8+2ep,+1
  const int eb = en >> 5, er = en & 31, j0 = ep * 8;

  bf16x8 xf[32];  // x A-fragments (holds x(step+1) at loop top)
  if (mat == 0) {
    const bf16* xb = queue + ((size_t)0 * N_ + blk * 32 + (lane & 31)) * C_ + kg;
#pragma unroll
    for (int kb = 0; kb < 32; ++kb) xf[kb] = *(const bf16x8*)(xb + kb * 16);
    {  // gx for step 0 -> slot 0
      f32x16 acc[2] = {};
#pragma unroll
      for (int kb = 0; kb < 32; ++kb)
        acc[kb & 1] = __builtin_amdgcn_mfma_f32_32x32x16_bf16(xf[kb], bw[kb], acc[kb & 1], 0, 0, 0);
      f32x16 asum = acc[0] + acc[1];
#pragma unroll
      for (int rg = 0; rg < 16; ++rg) {
        const int rl = (rg & 3) + 8 * (rg >> 2) + 4 * (lane >> 5);
        gx[0][blk][rl][col] = asum[rg];
      }
    }
    const bf16* xb1 = queue + ((size_t)1 * N_ + blk * 32 + (lane & 31)) * C_ + kg;
#pragma unroll
    for (int kb = 0; kb < 32; ++kb) xf[kb] = *(const bf16x8*)(xb1 + kb * 16);
  }

  for (int step = 0; step < Q_; ++step) {
    const int p3 = step % 3, p2 = step & 1;
    if (mat == 1) {
      f32x16 acc[2] = {};
      if (step > 0) {
        {  // poll flags: producers issued tag-(step) h before flag=step
          int v;
          int* fa = flags + lane;
          do {
            asm volatile("global_load_dword %0, %1, off sc0 sc1" : "=v"(v) : "v"(fa));
            asm volatile("s_waitcnt vmcnt(0)" ::: "memory");
          } while (!__all(v >= step));
        }
        __builtin_amdgcn_sched_barrier(0);
        const unsigned want = (unsigned)step << 16;
        unsigned* hb = Hp + ((size_t)(step & 1) * N_ + blk * 32 + (lane & 31)) * C_ + kg;
        uint4 ba[8], bb[8];
        ISSUE_CH(ba, 0);
        CH_STEP(0, ba, bb);
        CH_STEP(1, bb, ba);
        CH_STEP(2, ba, bb);
        CH_STEP(3, bb, ba);
        CH_STEP(4, ba, bb);
        CH_STEP(5, bb, ba);
        CH_STEP(6, ba, bb);
        CH_STEP(7, bb, ba);
      }
      f32x16 asum = acc[0] + acc[1];
#pragma unroll
      for (int rg = 0; rg < 16; ++rg) {
        const int rl = (rg & 3) + 8 * (rg >> 2) + 4 * (lane >> 5);
        gh[p2][blk][rl][col] = asum[rg];
      }
    } else if (step + 1 < Q_) {
      // x-waves: gates for step+1 from prefetched xf -> slot (step+1)%3
      f32x16 acc[2] = {};
#pragma unroll
      for (int kb = 0; kb < 32; ++kb)
        acc[kb & 1] = __builtin_amdgcn_mfma_f32_32x32x16_bf16(xf[kb], bw[kb], acc[kb & 1], 0, 0, 0);
      f32x16 asum = acc[0] + acc[1];
      const int ps = (step + 1) % 3;
#pragma unroll
      for (int rg = 0; rg < 16; ++rg) {
        const int rl = (rg & 3) + 8 * (rg >> 2) + 4 * (lane >> 5);
        gx[ps][blk][rl][col] = asum[rg];
      }
    }
    __syncthreads();  // S1: gh[p2] + gx[p3] ready

    {  // elementwise: n=en, channels w*8+2ep,+1; c-state in registers
      float g0 = gx[p3][eb][er][j0 + 0] + gh[p2][eb][er][j0 + 0] + bias[j0 + 0];
      float g1 = gx[p3][eb][er][j0 + 1] + gh[p2][eb][er][j0 + 1] + bias[j0 + 1];
      float g2 = gx[p3][eb][er][j0 + 2] + gh[p2][eb][er][j0 + 2] + bias[j0 + 2];
      float g3 = gx[p3][eb][er][j0 + 3] + gh[p2][eb][er][j0 + 3] + bias[j0 + 3];
      cs0 = sigf(g1) * cs0 + sigf(g0) * tanhf_(g2);
      float h0v = sigf(g3) * tanhf_(cs0);
      float g4 = gx[p3][eb][er][j0 + 4] + gh[p2][eb][er][j0 + 4] + bias[j0 + 4];
      float g5 = gx[p3][eb][er][j0 + 5] + gh[p2][eb][er][j0 + 5] + bias[j0 + 5];
      float g6 = gx[p3][eb][er][j0 + 6] + gh[p2][eb][er][j0 + 6] + bias[j0 + 6];
      float g7 = gx[p3][eb][er][j0 + 7] + gh[p2][eb][er][j0 + 7] + bias[j0 + 7];
      cs1 = sigf(g5) * cs1 + sigf(g4) * tanhf_(g6);
      float h1v = sigf(g7) * tanhf_(cs1);
      const unsigned lo = (unsigned)__builtin_bit_cast(unsigned short, (bf16)h0v);
      const unsigned hi = (unsigned)__builtin_bit_cast(unsigned short, (bf16)h1v);
      const unsigned tagv = (unsigned)(step + 1) << 16;
      uint2 pr; pr.x = tagv | lo; pr.y = tagv | hi;
      unsigned* Hq = Hp + ((size_t)((step + 1) & 1) * N_ + en) * C_ + w * 8 + ep * 2;
      asm volatile("global_store_dwordx2 %0, %1, off sc0 sc1" :: "v"(Hq), "v"(pr) : "memory");
      *((unsigned*)hs + ((size_t)step * N_ + en) * (C_ / 2) + w * 4 + ep) = (hi << 16) | lo;
    }
    // no drain: tag-verify covers h in flight; flag published after per-WG fan-in
    if (step + 1 < Q_) {
      if (lane == 0) {
        if (atomicAdd(&ldsCnt[step], 1) == 3) {  // last wave of this WG
          int fv = step + 1;
          int* fp = flags + w;
          asm volatile("global_store_dword %0, %1, off sc0 sc1" :: "v"(fp), "v"(fv) : "memory");
        }
      }
      if (mat == 0 && step + 2 < Q_) {  // prefetch x(step+2)
        const bf16* xb = queue + ((size_t)(step + 2) * N_ + blk * 32 + (lane & 31)) * C_ + kg;
#pragma unroll
        for (int kb = 0; kb < 32; ++kb) xf[kb] = *(const bf16x8*)(xb + kb * 16);
      }
    }
    // no S2: gx triple-buffer + gh parity buffer remove the LDS hazards
  }
}

// ---------------- stage 5: LayerNorm + decode ----------------
__global__ __launch_bounds__(256) void k_lndec(const bf16* __restrict__ hs,
    const float* __restrict__ gamma, const float* __restrict__ beta,
    const float* __restrict__ Wdec, const float* __restrict__ bdec,
    float* __restrict__ out) {
  const int wid = threadIdx.x >> 6, lane = threadIdx.x & 63;
  const int row = blockIdx.x * 4 + wid;
  const bf16* hrow = hs + (size_t)row * C_ + lane * 8;
  bf16x8 hv = *(const bf16x8*)hrow;
  float h[8];
  float sm = 0.f, sq = 0.f;
#pragma unroll
  for (int j = 0; j < 8; ++j) {
    h[j] = (float)hv[j];
    sm += h[j];
    sq += h[j] * h[j];
  }
#pragma unroll
  for (int m = 32; m >= 1; m >>= 1) {
    sm += __shfl_xor(sm, m);
    sq += __shfl_xor(sq, m);
  }
  const float mu = sm * (1.f / C_);
  const float var = sq * (1.f / C_) - mu * mu;
  const float rs = 1.f / sqrtf(var + 1e-5f);
  float o[V_] = {};
#pragma unroll
  for (int j = 0; j < 8; ++j) {
    const int cj = lane * 8 + j;
    const float nv = (h[j] - mu) * rs * gamma[cj] + beta[cj];
    const float* wr = Wdec + (size_t)cj * V_;
#pragma unroll
    for (int v = 0; v < V_; ++v) o[v] += nv * wr[v];
  }
#pragma unroll
  for (int v = 0; v < V_; ++v) {
#pragma unroll
    for (int m = 32; m >= 1; m >>= 1) o[v] += __shfl_xor(o[v], m);
  }
  if (lane == 0) {
#pragma unroll
    for (int v = 0; v < V_; ++v) out[(size_t)row * V_ + v] = o[v] + bdec[v];
  }
}

extern "C" void kernel_launch(void* const* d_in, const int* in_sizes, int n_in,
                              void* d_out, int out_size, void* d_ws, size_t ws_size,
                              hipStream_t stream) {
  (void)in_sizes; (void)n_in; (void)out_size; (void)ws_size;
  const float* mem  = (const float*)d_in[0];
  const float* Wact = (const float*)d_in[1];
  const float* bact = (const float*)d_in[2];
  const float* Wih  = (const float*)d_in[3];
  const float* Whh  = (const float*)d_in[4];
  const float* bih  = (const float*)d_in[5];
  const float* bhh  = (const float*)d_in[6];
  const float* gam  = (const float*)d_in[7];
  const float* bet  = (const float*)d_in[8];
  const float* Wdec = (const float*)d_in[9];
  const float* bdec = (const float*)d_in[10];
  float* out = (float*)d_out;

  char* ws = (char*)d_ws;
  float* A0    = (float*)(ws + OFF_A0);
  float* A1    = (float*)(ws + OFF_A1);
  bf16* Pw     = (bf16*)(ws + OFF_PW);
  bf16* qu     = (bf16*)(ws + OFF_QU);
  unsigned* Hp = (unsigned*)(ws + OFF_HP);
  bf16* hs     = (bf16*)(ws + OFF_HS);
  int* ctrl    = (int*)(ws + OFF_CTRL);

  hipMemsetAsync(ctrl, 0, 4096, stream);
  k_actions<<<(S_ * N_) / 4, 256, 0, stream>>>(mem, Wact, bact, A0, A1);
  k_posvec<<<N_, 256, 0, stream>>>(A0, A1, Pw);
  k_queue<<<N_ * 32, 256, 0, stream>>>(Pw, mem, qu);
  k_lstm<<<64, 256, 0, stream>>>(qu, Wih, Whh, bih, bhh, Hp, hs, ctrl);
  k_lndec<<<(Q_ * N_) / 4, 256, 0, stream>>>(hs, gam, bet, Wdec, bdec, out);
}